// Round 1
// baseline (244.341 us; speedup 1.0000x reference)
//
#include <hip/hip_runtime.h>

typedef __attribute__((ext_vector_type(8)))  _Float16 half8;
typedef __attribute__((ext_vector_type(4)))  _Float16 half4;
typedef __attribute__((ext_vector_type(16))) float    f32x16;

#define G_LATENT 256
#define EMB      512
#define WFLAT    36864   // 64*64*3*3 per-sample weight count

// ---------------------------------------------------------------------------
// K1: hdn[s][j] = relu(emb[s] . w1_w[j] + w1_b[j])   (fp32, 32x256)
// ---------------------------------------------------------------------------
__global__ __launch_bounds__(256) void k1_hdn(
    const float* __restrict__ emb, const float* __restrict__ w1w,
    const float* __restrict__ w1b, float* __restrict__ hdn)
{
    const int s = blockIdx.x;
    const int j = threadIdx.x;
    const float4* e4 = (const float4*)(emb + (size_t)s * EMB);
    const float4* w4 = (const float4*)(w1w + (size_t)j * EMB);
    float acc = 0.f;
#pragma unroll 8
    for (int k = 0; k < EMB / 4; ++k) {
        float4 a = e4[k], b = w4[k];
        acc += a.x * b.x + a.y * b.y + a.z * b.z + a.w * b.w;
    }
    acc += w1b[j];
    hdn[s * G_LATENT + j] = fmaxf(acc, 0.f);
}

// ---------------------------------------------------------------------------
// K2: weights = hdn @ w2_w^T + w2_b, written as f16 MFMA A-fragments.
// GEMM: M=32 (samples) x N=36864 (r) x K=256 via mfma_f32_32x32x16_f16.
// Fragment element mapping (MUST match k3's consumption):
//   frag(s, khw, kb, octile): lane l, elem e holds
//     W[s][oc = octile*32 + (l&31)][ic = kb*16 + (e>>2)*8 + 4*(l>>5) + (e&3)][khw]
// flat = ((((s*9+khw)*4+kb)*2+octile)*64 + lane)*8 + e
// ---------------------------------------------------------------------------
__global__ __launch_bounds__(256) void k2_wfrag(
    const float* __restrict__ hdn, const float* __restrict__ w2w,
    const float* __restrict__ w2b, _Float16* __restrict__ wfrag)
{
    const int tid  = threadIdx.x;
    const int lane = tid & 63;
    const int h    = lane >> 5, n31 = lane & 31;
    const int rtile = blockIdx.x * 4 + (tid >> 6);
    const int r     = rtile * 32 + n31;

    // A fragments from hdn: m = lane&31 = sample, k mapping g(h,e)=(e>>2)*8+4h+(e&3)
    half8 afr[16];
#pragma unroll
    for (int kb = 0; kb < 16; ++kb) {
        const float* p = hdn + n31 * G_LATENT + kb * 16 + 4 * h;
        float4 q0 = *(const float4*)p;
        float4 q1 = *(const float4*)(p + 8);
        half8 a;
        a[0] = (_Float16)q0.x; a[1] = (_Float16)q0.y;
        a[2] = (_Float16)q0.z; a[3] = (_Float16)q0.w;
        a[4] = (_Float16)q1.x; a[5] = (_Float16)q1.y;
        a[6] = (_Float16)q1.z; a[7] = (_Float16)q1.w;
        afr[kb] = a;
    }

    f32x16 acc = {0,0,0,0,0,0,0,0,0,0,0,0,0,0,0,0};
    const float* wrow = w2w + (size_t)r * G_LATENT;
#pragma unroll
    for (int kb = 0; kb < 16; ++kb) {
        float4 q0 = *(const float4*)(wrow + kb * 16 + 4 * h);
        float4 q1 = *(const float4*)(wrow + kb * 16 + 4 * h + 8);
        half8 bfr;
        bfr[0] = (_Float16)q0.x; bfr[1] = (_Float16)q0.y;
        bfr[2] = (_Float16)q0.z; bfr[3] = (_Float16)q0.w;
        bfr[4] = (_Float16)q1.x; bfr[5] = (_Float16)q1.y;
        bfr[6] = (_Float16)q1.z; bfr[7] = (_Float16)q1.w;
        acc = __builtin_amdgcn_mfma_f32_32x32x16_f16(afr[kb], bfr, acc, 0, 0, 0);
    }

    const float bias = w2b[r];
    // decode r -> (oc, ic, khw); r = oc*576 + ic*9 + khw
    const int oc  = r / 576;
    const int rem = r - oc * 576;
    const int ic  = rem / 9;
    const int khw = rem - ic * 9;
    const int octile = oc >> 5, l31 = oc & 31;
    const int kb4 = ic >> 4, i16 = ic & 15;
    const int hh  = (i16 >> 2) & 1;
    const int e   = (i16 & 3) + 4 * (i16 >> 3);
    const int lanep = l31 + 32 * hh;
#pragma unroll
    for (int g = 0; g < 16; ++g) {
        const int srow = (g & 3) + 8 * (g >> 2) + 4 * h;  // C/D row (HW-verified)
        const size_t idx =
            (((((size_t)srow * 9 + khw) * 4 + kb4) * 2 + octile) * 64 + lanep) * 8 + e;
        wfrag[idx] = (_Float16)(acc[g] + bias);
    }
}

// ---------------------------------------------------------------------------
// K3: per-sample conv as implicit GEMM with mfma_f32_32x32x16_f16.
// Block: sample s, 12 output rows x 32 output cols, all 64 oc. 4 waves;
// wave wv owns rows wv*3..wv*3+2 (3 n-tiles), both oc-tiles (R_oc=2,R_n=3).
// x tile staged to LDS channel-last f16, channel-quad permuted + XOR swizzle
// so B fragments are single 16B ds_read_b128.
// ---------------------------------------------------------------------------
#define TRO  12
#define XRN  14           // 12 + 2 halo rows
#define XCN  34           // 32 + 2 halo cols
#define NSPX (XRN * XCN)  // 476 spatial slots, 128B (64 ch * f16) each

__global__ __launch_bounds__(256, 2) void k3_conv(
    const float* __restrict__ x, const _Float16* __restrict__ wfrag,
    float* __restrict__ out)
{
    __shared__ __align__(16) unsigned char lds[NSPX * 128];  // 60928 B

    const int b  = blockIdx.x;
    const int wg = (b & 7) * 96 + (b >> 3);   // bijective XCD swizzle (768 % 8 == 0)
    const int ct = wg % 3;
    const int rt = (wg / 3) & 7;
    const int s  = wg / 24;
    const int rbase = rt * TRO, cbase = ct * 32;
    const int tid = threadIdx.x;

    // ---- stage x tile -> LDS (fp32 -> f16), zero-pad OOB -------------------
    // i -> (spx = (i&15)+16*(i>>8), quad = (i>>4)&15); lanes 0-15 consecutive
    // spx (coalesced global), quads vary across lane groups (spreads banks).
    for (int i = tid; i < 30 * 256; i += 256) {
        const int spx = (i & 15) + ((i >> 8) << 4);
        if (spx < NSPX) {
            const int q  = (i >> 4) & 15;
            const int xr = spx / XCN;
            const int xc = spx - xr * XCN;
            const int gr = rbase + xr, gc = cbase + xc;
            float f0 = 0.f, f1 = 0.f, f2 = 0.f, f3 = 0.f;
            if (gr < 96 && gc < 96) {
                const float* px = x + (size_t)(s * 64 + q * 4) * 9216 + gr * 96 + gc;
                f0 = px[0];
                f1 = px[9216];
                f2 = px[2 * 9216];
                f3 = px[3 * 9216];
            }
            half4 hv;
            hv[0] = (_Float16)f0; hv[1] = (_Float16)f1;
            hv[2] = (_Float16)f2; hv[3] = (_Float16)f3;
            // quad q (ic=4q..4q+3) -> byte base: (q>>2)*32 + {0,16,8,24}[q&3]
            const int qoff = ((q >> 2) << 5) + ((q & 1) << 4) + (((q >> 1) & 1) << 3);
            const int addr = ((spx << 7) + qoff) ^ ((spx & 7) << 4);
            *(half4*)(lds + addr) = hv;
        }
    }
    __syncthreads();

    const int lane = tid & 63, wv = tid >> 6;
    const int h = lane >> 5, n31 = lane & 31;

    const f32x16 z16 = {0,0,0,0,0,0,0,0,0,0,0,0,0,0,0,0};
    f32x16 acc[2][3];
#pragma unroll
    for (int o = 0; o < 2; ++o)
#pragma unroll
        for (int n = 0; n < 3; ++n) acc[o][n] = z16;

    const half8* __restrict__ A = (const half8*)(wfrag + (size_t)s * WFLAT);

    for (int khw = 0; khw < 9; ++khw) {
        const int kh = khw / 3;
        const int kw = khw - kh * 3;
        const int rowb = (wv * 3 + kh) * XCN + n31 + kw;
#pragma unroll
        for (int kb = 0; kb < 4; ++kb) {
            const half8 a0 = A[((khw * 4 + kb) * 2 + 0) * 64 + lane];
            const half8 a1 = A[((khw * 4 + kb) * 2 + 1) * 64 + lane];
#pragma unroll
            for (int n = 0; n < 3; ++n) {
                const int spx  = rowb + n * XCN;
                const int addr = ((spx << 7) + (kb << 5) + (h << 4)) ^ ((spx & 7) << 4);
                const half8 bb = *(const half8*)(lds + addr);
                acc[0][n] = __builtin_amdgcn_mfma_f32_32x32x16_f16(a0, bb, acc[0][n], 0, 0, 0);
                acc[1][n] = __builtin_amdgcn_mfma_f32_32x32x16_f16(a1, bb, acc[1][n], 0, 0, 0);
            }
        }
    }

    // ---- store (C/D: col = lane&31 = position, row = (g&3)+8*(g>>2)+4h = oc)
    const int ocol = cbase + n31;
    if (ocol < 94) {
#pragma unroll
        for (int ot = 0; ot < 2; ++ot) {
#pragma unroll
            for (int n = 0; n < 3; ++n) {
                const int orow = rbase + wv * 3 + n;
                if (orow < 94) {
                    float* po = out + (size_t)(s * 64 + ot * 32 + 4 * h) * 8836
                                    + orow * 94 + ocol;
#pragma unroll
                    for (int g = 0; g < 16; ++g) {
                        const int od = (g & 3) + 8 * (g >> 2);
                        po[(size_t)od * 8836] = acc[ot][n][g];
                    }
                }
            }
        }
    }
}

// ---------------------------------------------------------------------------
extern "C" void kernel_launch(void* const* d_in, const int* in_sizes, int n_in,
                              void* d_out, int out_size, void* d_ws, size_t ws_size,
                              hipStream_t stream)
{
    (void)in_sizes; (void)n_in; (void)out_size; (void)ws_size;
    const float* emb = (const float*)d_in[0];
    const float* x   = (const float*)d_in[1];
    const float* w1w = (const float*)d_in[2];
    const float* w1b = (const float*)d_in[3];
    const float* w2w = (const float*)d_in[4];
    const float* w2b = (const float*)d_in[5];
    float* out = (float*)d_out;

    float*    hdn   = (float*)d_ws;                          // 32 KiB
    _Float16* wfrag = (_Float16*)((char*)d_ws + 32 * 1024);  // 2.25 MiB

    k1_hdn<<<32, 256, 0, stream>>>(emb, w1w, w1b, hdn);
    k2_wfrag<<<288, 256, 0, stream>>>(hdn, w2w, w2b, wfrag);
    k3_conv<<<768, 256, 0, stream>>>(x, wfrag, out);
}

// Round 2
// 227.050 us; speedup vs baseline: 1.0762x; 1.0762x over previous
//
#include <hip/hip_runtime.h>

typedef __attribute__((ext_vector_type(8)))  _Float16 half8;
typedef __attribute__((ext_vector_type(4)))  _Float16 half4;
typedef __attribute__((ext_vector_type(16))) float    f32x16;

#define G_LATENT 256
#define EMB      512
#define WFLAT    36864   // 64*64*3*3 per-sample weight count

// ---------------------------------------------------------------------------
// K1: hdn = relu(emb @ w1_w^T + b), emitted directly in f16 A-fragment order:
//   hdn16[(kb*64 + s + 32*h)*8 + e] = hdn[s][kb*16 + (e>>2)*8 + 4h + (e&3)]
// ---------------------------------------------------------------------------
__global__ __launch_bounds__(256) void k1_hdn(
    const float* __restrict__ emb, const float* __restrict__ w1w,
    const float* __restrict__ w1b, _Float16* __restrict__ hdn16)
{
    const int s = blockIdx.x;
    const int j = threadIdx.x;
    const float4* e4 = (const float4*)(emb + (size_t)s * EMB);
    const float4* w4 = (const float4*)(w1w + (size_t)j * EMB);
    float a0 = 0.f, a1 = 0.f;
#pragma unroll 8
    for (int k = 0; k < EMB / 4; k += 2) {
        float4 a = e4[k],     b = w4[k];
        float4 c = e4[k + 1], d = w4[k + 1];
        a0 += a.x * b.x + a.y * b.y + a.z * b.z + a.w * b.w;
        a1 += c.x * d.x + c.y * d.y + c.z * d.z + c.w * d.w;
    }
    const float acc = fmaxf(a0 + a1 + w1b[j], 0.f);
    const int kb = j >> 4;
    const int h  = (j >> 2) & 1;
    const int e  = (j & 3) + 4 * ((j >> 3) & 1);
    hdn16[(kb * 64 + s + 32 * h) * 8 + e] = (_Float16)acc;
}

// ---------------------------------------------------------------------------
// K2 (brick-based): weights = hdn @ w2_w^T + w2_b -> f16 MFMA A-fragments.
// Grid = 9(khw) x 4(kbc) x 2(oct) x 2(ihalf) = 144 blocks. Block computes a
// 32s x 256r tile where r spans 32 oc x 8 ic_off of one brick. Staged w2w
// rows live in LDS as [kchunk(kb16,h)][row][8 halves] -> conflict-free reads.
// Epilogue transposes through LDS so global stores are coalesced half4.
// ---------------------------------------------------------------------------
__global__ __launch_bounds__(256) void k2_wfrag(
    const _Float16* __restrict__ hdn16, const float* __restrict__ w2w,
    const float* __restrict__ w2b, _Float16* __restrict__ wfrag)
{
    __shared__ __align__(16) _Float16 sm[8 * 256 * 8];  // 32 KiB

    const int b     = blockIdx.x;
    const int ihalf = b & 1;
    const int oct   = (b >> 1) & 1;
    const int kbc   = (b >> 2) & 3;
    const int khw   = b >> 4;          // 0..8

    const int t = threadIdx.x, lane = t & 63, wv = t >> 6;
    const int h = lane >> 5, l31 = lane & 31;

    // staged row for this thread: row t = ic_off*32 + oc31
    const int oc31 = t & 31, icof = t >> 5;
    const size_t rrow = (size_t)(oct * 32 + oc31) * 576
                      + (size_t)(kbc * 16 + ihalf * 8 + icof) * 9 + khw;
    const float* wrow = w2w + rrow * G_LATENT;

    // bias per MFMA column (nt = wv*2 + ntl, column = nt*32 + l31)
    float bias[2];
#pragma unroll
    for (int ntl = 0; ntl < 2; ++ntl) {
        const int nt = wv * 2 + ntl;
        const size_t rc = (size_t)(oct * 32 + l31) * 576
                        + (size_t)(kbc * 16 + ihalf * 8 + nt) * 9 + khw;
        bias[ntl] = w2b[rc];
    }

    const f32x16 z16 = {0,0,0,0,0,0,0,0,0,0,0,0,0,0,0,0};
    f32x16 acc[2] = {z16, z16};

    float4 ld[2][16];
#pragma unroll
    for (int u = 0; u < 16; ++u) ld[0][u] = ((const float4*)wrow)[u];

    const half8* __restrict__ hfr = (const half8*)hdn16;

#pragma unroll
    for (int kc = 0; kc < 4; ++kc) {
        __syncthreads();               // prev chunk's reads finished
        if (kc < 3) {
            const float4* nxt = (const float4*)(wrow + (kc + 1) * 64);
#pragma unroll
            for (int u = 0; u < 16; ++u) ld[(kc + 1) & 1][u] = nxt[u];
        }
        // cvt + LDS write, fragment k-order: chunk(kb16,hh) pos p -> k =
        // kb16*16 + (p>>2)*8 + 4*hh + (p&3)
#pragma unroll
        for (int kb16 = 0; kb16 < 4; ++kb16) {
#pragma unroll
            for (int hh = 0; hh < 2; ++hh) {
                const float4 lo = ld[kc & 1][kb16 * 4 + hh];
                const float4 hi = ld[kc & 1][kb16 * 4 + 2 + hh];
                half8 c;
                c[0] = (_Float16)lo.x; c[1] = (_Float16)lo.y;
                c[2] = (_Float16)lo.z; c[3] = (_Float16)lo.w;
                c[4] = (_Float16)hi.x; c[5] = (_Float16)hi.y;
                c[6] = (_Float16)hi.z; c[7] = (_Float16)hi.w;
                *(half8*)&sm[((kb16 * 2 + hh) * 256 + t) * 8] = c;
            }
        }
        __syncthreads();
#pragma unroll
        for (int kb16 = 0; kb16 < 4; ++kb16) {
            const half8 af = hfr[(kc * 4 + kb16) * 64 + lane];
#pragma unroll
            for (int ntl = 0; ntl < 2; ++ntl) {
                const int lr = (wv * 2 + ntl) * 32 + l31;
                const half8 bf = *(const half8*)&sm[((kb16 * 2 + h) * 256 + lr) * 8];
                acc[ntl] = __builtin_amdgcn_mfma_f32_32x32x16_f16(af, bf, acc[ntl], 0, 0, 0);
            }
        }
    }

    __syncthreads();
    // ---- epilogue: scatter to LDS in fragment order (2B writes, cheap) ----
#pragma unroll
    for (int ntl = 0; ntl < 2; ++ntl) {
        const int nt    = wv * 2 + ntl;          // = ic_off
        const int lanep = l31 + 32 * (nt >> 2);  // frag lane'
        const int elow  = nt & 3;
#pragma unroll
        for (int g = 0; g < 16; ++g) {
            const int srow = (g & 3) + 8 * (g >> 2) + 4 * h;  // sample
            sm[(srow * 64 + lanep) * 4 + elow] = (_Float16)(acc[ntl][g] + bias[ntl]);
        }
    }
    __syncthreads();
    // ---- read back coalesced, store half4 to global ----
#pragma unroll
    for (int i = 0; i < 8; ++i) {
        const int c = t + 256 * i;               // 0..2047
        const int s  = c >> 6, lp = c & 63;
        const half4 hv = *(const half4*)&sm[c * 4];
        _Float16* dst = wfrag + ((((size_t)s * 9 + khw) * 4 + kbc) * 2 + oct) * 512
                              + lp * 8 + ihalf * 4;
        *(half4*)dst = hv;
    }
}

// ---------------------------------------------------------------------------
// K3: per-sample conv as implicit GEMM, mfma_f32_32x32x16_f16.
// Tile: 64 oc x 12 rows x 32 cols. Clamped tile origins -> branchless, all
// loads/stores in-bounds (overlap rows/cols recomputed identically).
// LDS layout [xr 14][kb 4][h 2][xc 36][8 halves] -> conflict-free B reads.
// ---------------------------------------------------------------------------
__global__ __launch_bounds__(256, 2) void k3_conv(
    const float* __restrict__ x, const _Float16* __restrict__ wfrag,
    float* __restrict__ out)
{
    __shared__ __align__(16) _Float16 lds[14 * 8 * 36 * 8];  // 64512 B

    const int b  = blockIdx.x;
    const int wg = (b & 7) * 96 + (b >> 3);   // bijective XCD swizzle (768%8==0)
    const int ct = wg % 3;
    const int rt = (wg / 3) & 7;
    const int s  = wg / 24;
    const int rbase  = (rt < 7) ? rt * 12 : 82;
    const int wstart = (ct == 0) ? 0 : (ct == 1) ? 32 : 60;
    const int dlt    = (ct == 2) ? 2 : 0;
    const int tid = threadIdx.x;

    // ---- stage x tile -> LDS (float4 loads, fp32->f16, branchless) --------
    if (tid < 252) {
        const int p9 = tid % 9, q9 = tid / 9;   // part (col group), piece group
        const float* xs = x + (size_t)s * 64 * 9216 + (size_t)rbase * 96
                            + wstart + p9 * 4;
#pragma unroll 4
        for (int i = 0; i < 32; ++i) {
            const int piece = q9 + 28 * i;      // = xr*64 + ch, 0..895
            const int xr = piece >> 6, ch = piece & 63;
            const float4 v = *(const float4*)(xs + (size_t)ch * 9216 + xr * 96);
            const int kb = ch >> 4, c16 = ch & 15;
            const int hh = (c16 >> 2) & 1;
            const int pz = (c16 & 3) + 4 * ((c16 >> 3) & 1);
            const int base = ((xr * 8 + kb * 2 + hh) * 36 + p9 * 4) * 8 + pz;
            lds[base]      = (_Float16)v.x;
            lds[base + 8]  = (_Float16)v.y;
            lds[base + 16] = (_Float16)v.z;
            lds[base + 24] = (_Float16)v.w;
        }
    }
    __syncthreads();

    const int lane = tid & 63, wv = tid >> 6;
    const int h = lane >> 5, n31 = lane & 31;

    const f32x16 z16 = {0,0,0,0,0,0,0,0,0,0,0,0,0,0,0,0};
    f32x16 acc[2][3];
#pragma unroll
    for (int o = 0; o < 2; ++o)
#pragma unroll
        for (int n = 0; n < 3; ++n) acc[o][n] = z16;

    const half8* __restrict__ A = (const half8*)(wfrag + (size_t)s * WFLAT);

    for (int kh = 0; kh < 3; ++kh) {
        for (int kw = 0; kw < 3; ++kw) {
            const int khw = kh * 3 + kw;
            const int xc  = dlt + n31 + kw;
#pragma unroll
            for (int kb = 0; kb < 4; ++kb) {
                const half8 a0 = A[((khw * 4 + kb) * 2 + 0) * 64 + lane];
                const half8 a1 = A[((khw * 4 + kb) * 2 + 1) * 64 + lane];
#pragma unroll
                for (int n = 0; n < 3; ++n) {
                    const int xr = wv * 3 + n + kh;
                    const half8 bb =
                        *(const half8*)&lds[((xr * 8 + kb * 2 + h) * 36 + xc) * 8];
                    acc[0][n] = __builtin_amdgcn_mfma_f32_32x32x16_f16(a0, bb, acc[0][n], 0, 0, 0);
                    acc[1][n] = __builtin_amdgcn_mfma_f32_32x32x16_f16(a1, bb, acc[1][n], 0, 0, 0);
                }
            }
        }
    }

    // ---- store (C/D: col=lane&31 -> position, row=(g&3)+8*(g>>2)+4h -> oc)
    const int ocol = wstart + dlt + n31;       // always < 94
#pragma unroll
    for (int ot = 0; ot < 2; ++ot) {
#pragma unroll
        for (int n = 0; n < 3; ++n) {
            const int orow = rbase + wv * 3 + n;   // always < 94
            float* po = out + (size_t)(s * 64 + ot * 32 + 4 * h) * 8836
                            + orow * 94 + ocol;
#pragma unroll
            for (int g = 0; g < 16; ++g) {
                const int od = (g & 3) + 8 * (g >> 2);
                po[(size_t)od * 8836] = acc[ot][n][g];
            }
        }
    }
}

// ---------------------------------------------------------------------------
extern "C" void kernel_launch(void* const* d_in, const int* in_sizes, int n_in,
                              void* d_out, int out_size, void* d_ws, size_t ws_size,
                              hipStream_t stream)
{
    (void)in_sizes; (void)n_in; (void)out_size; (void)ws_size;
    const float* emb = (const float*)d_in[0];
    const float* x   = (const float*)d_in[1];
    const float* w1w = (const float*)d_in[2];
    const float* w1b = (const float*)d_in[3];
    const float* w2w = (const float*)d_in[4];
    const float* w2b = (const float*)d_in[5];
    float* out = (float*)d_out;

    _Float16* hdn16 = (_Float16*)d_ws;                        // 16 KiB
    _Float16* wfrag = (_Float16*)((char*)d_ws + 32 * 1024);   // 2.25 MiB

    k1_hdn<<<32, 256, 0, stream>>>(emb, w1w, w1b, hdn16);
    k2_wfrag<<<144, 256, 0, stream>>>(hdn16, w2w, w2b, wfrag);
    k3_conv<<<768, 256, 0, stream>>>(x, wfrag, out);
}